// Round 4
// baseline (19796.738 us; speedup 1.0000x reference)
//
#include <hip/hip_runtime.h>
#include <hip/hip_bf16.h>

#define S_LEN 8192
#define CLEN 16
#define WDIM 256
#define CDIM 64
#define CHID 128
#define WHID 512
#define GDIM 2048   // 4*WHID
#define NTAG 64
#define KDIM 384    // WDIM + CHID
#define NWG 32      // workgroups in sequential kernel

typedef unsigned long long u64;

__device__ __forceinline__ float sigmoidf_(float x) {
  return 1.0f / (1.0f + __expf(-x));
}
__device__ __forceinline__ float tanhf_(float x) {
  // safe tanh: 1 - 2/(e^{2x}+1); correct limits at +-inf without NaN
  return 1.0f - 2.0f / (__expf(2.0f * x) + 1.0f);
}

// ---------------------------------------------------------------------------
// K1: batched char LSTM. 16 words per block (two groups of 8), 256 threads.
// ---------------------------------------------------------------------------
__global__ __launch_bounds__(256)
void char_lstm_kernel(const int* __restrict__ chars, const int* __restrict__ lengths,
                      const float* __restrict__ emb, const float* __restrict__ Wih,
                      const float* __restrict__ Whh, const float* __restrict__ bih,
                      const float* __restrict__ bhh, float* __restrict__ cf)
{
  __shared__ float xs[16][CDIM];
  __shared__ float hsm[16][CHID];
  __shared__ int cidx[16];
  __shared__ int lens[16];
  const int tid = threadIdx.x;
  const int grp = tid >> 7;      // 0..1 (word group)
  const int j = tid & 127;       // hidden index
  const int wb = blockIdx.x * 16;

  for (int i = tid; i < 16 * CHID; i += 256) (&hsm[0][0])[i] = 0.f;
  if (tid < 16) lens[tid] = lengths[wb + tid];
  float c[8];
#pragma unroll
  for (int w = 0; w < 8; ++w) c[w] = 0.f;
  const float bi = bih[j] + bhh[j];
  const float bf = bih[CHID + j] + bhh[CHID + j];
  const float bg = bih[2 * CHID + j] + bhh[2 * CHID + j];
  const float bo = bih[3 * CHID + j] + bhh[3 * CHID + j];

  for (int t = 0; t < CLEN; ++t) {
    __syncthreads();
    if (tid < 16) cidx[tid] = chars[(wb + tid) * CLEN + t];
    __syncthreads();
    {
      int e = tid * 4;
      int wi = e >> 6;
      int k = e & 63;
      const float4 v = *(const float4*)(emb + (size_t)cidx[wi] * CDIM + k);
      *(float4*)(&xs[wi][k]) = v;
    }
    __syncthreads();
    float ai[8], af[8], ag[8], ao[8];
#pragma unroll
    for (int w = 0; w < 8; ++w) { ai[w] = bi; af[w] = bf; ag[w] = bg; ao[w] = bo; }
    // x part (K = 64)
    for (int k = 0; k < CDIM; k += 4) {
      float4 w0 = *(const float4*)(Wih + (size_t)j * CDIM + k);
      float4 w1 = *(const float4*)(Wih + (size_t)(CHID + j) * CDIM + k);
      float4 w2 = *(const float4*)(Wih + (size_t)(2 * CHID + j) * CDIM + k);
      float4 w3 = *(const float4*)(Wih + (size_t)(3 * CHID + j) * CDIM + k);
#pragma unroll
      for (int s = 0; s < 4; ++s) {
        float wiv = (&w0.x)[s], wfv = (&w1.x)[s], wgv = (&w2.x)[s], wov = (&w3.x)[s];
#pragma unroll
        for (int w = 0; w < 8; ++w) {
          float xv = xs[grp * 8 + w][k + s];   // wave-uniform -> LDS broadcast
          ai[w] = fmaf(wiv, xv, ai[w]);
          af[w] = fmaf(wfv, xv, af[w]);
          ag[w] = fmaf(wgv, xv, ag[w]);
          ao[w] = fmaf(wov, xv, ao[w]);
        }
      }
    }
    // h part (K = 128)
    for (int k = 0; k < CHID; k += 4) {
      float4 w0 = *(const float4*)(Whh + (size_t)j * CHID + k);
      float4 w1 = *(const float4*)(Whh + (size_t)(CHID + j) * CHID + k);
      float4 w2 = *(const float4*)(Whh + (size_t)(2 * CHID + j) * CHID + k);
      float4 w3 = *(const float4*)(Whh + (size_t)(3 * CHID + j) * CHID + k);
#pragma unroll
      for (int s = 0; s < 4; ++s) {
        float wiv = (&w0.x)[s], wfv = (&w1.x)[s], wgv = (&w2.x)[s], wov = (&w3.x)[s];
#pragma unroll
        for (int w = 0; w < 8; ++w) {
          float hv = hsm[grp * 8 + w][k + s];
          ai[w] = fmaf(wiv, hv, ai[w]);
          af[w] = fmaf(wfv, hv, af[w]);
          ag[w] = fmaf(wgv, hv, ag[w]);
          ao[w] = fmaf(wov, hv, ao[w]);
        }
      }
    }
    __syncthreads();
#pragma unroll
    for (int w = 0; w < 8; ++w) {
      if (t < lens[grp * 8 + w]) {
        float iv = sigmoidf_(ai[w]);
        float fv = sigmoidf_(af[w]);
        float gv = tanhf_(ag[w]);
        float ov = sigmoidf_(ao[w]);
        c[w] = fv * c[w] + iv * gv;
        hsm[grp * 8 + w][j] = ov * tanhf_(c[w]);
      }
    }
  }
#pragma unroll
  for (int w = 0; w < 8; ++w)
    cf[(size_t)(wb + grp * 8 + w) * CHID + j] = c[w];   // feature = final CELL state
}

// ---------------------------------------------------------------------------
// K2: G_x[t][g] = [word_emb[x[t]] | char_feat[t]] @ w_Wih^T + (bih+bhh)
// ---------------------------------------------------------------------------
#define BM 64
#define BN 64
#define BK 32
__global__ __launch_bounds__(256)
void gx_gemm_kernel(const int* __restrict__ x, const float* __restrict__ word_emb,
                    const float* __restrict__ char_feat, const float* __restrict__ Wih,
                    const float* __restrict__ bih, const float* __restrict__ bhh,
                    float* __restrict__ Gx)
{
  __shared__ float As[BK][BM + 1];
  __shared__ float Bs[BK][BN + 1];
  __shared__ int xidx[BM];
  const int tid = threadIdx.x;
  const int tx = tid & 15, ty = tid >> 4;
  const int m0 = blockIdx.y * BM;
  const int n0 = blockIdx.x * BN;
  if (tid < BM) xidx[tid] = x[m0 + tid];
  float acc[4][4] = {};
  for (int k0 = 0; k0 < KDIM; k0 += BK) {
    __syncthreads();
    {
      int i = tid >> 5;
      int kk = tid & 31;
#pragma unroll
      for (int l = 0; l < 8; ++l) {
        int row = i + l * 8;
        int k = k0 + kk;
        int tt = m0 + row;
        float v = (k < WDIM) ? word_emb[(size_t)xidx[row] * WDIM + k]
                             : char_feat[(size_t)tt * CHID + (k - WDIM)];
        As[kk][row] = v;
      }
    }
    {
      int jjj = tid >> 5;
      int kk = tid & 31;
#pragma unroll
      for (int l = 0; l < 8; ++l) {
        int col = jjj + l * 8;
        Bs[kk][col] = Wih[(size_t)(n0 + col) * KDIM + k0 + kk];
      }
    }
    __syncthreads();
#pragma unroll
    for (int kk = 0; kk < BK; ++kk) {
      float a[4], b[4];
#pragma unroll
      for (int m = 0; m < 4; ++m) a[m] = As[kk][ty * 4 + m];
#pragma unroll
      for (int n = 0; n < 4; ++n) b[n] = Bs[kk][tx * 4 + n];
#pragma unroll
      for (int m = 0; m < 4; ++m)
#pragma unroll
        for (int n = 0; n < 4; ++n)
          acc[m][n] = fmaf(a[m], b[n], acc[m][n]);
    }
  }
#pragma unroll
  for (int n = 0; n < 4; ++n) {
    int g = n0 + tx * 4 + n;
    float bias = bih[g] + bhh[g];
#pragma unroll
    for (int m = 0; m < 4; ++m) {
      int tt = m0 + ty * 4 + m;
      Gx[(size_t)tt * GDIM + g] = acc[m][n] + bias;
    }
  }
}

// ---------------------------------------------------------------------------
// K3: sequential word LSTM, v4: in-wave reduction + parallel finalize +
// VGPR-pinned weights + staggered conflict-free LDS staging.
//
// 32 WGs x 256 thr. WG w owns h[16w..16w+16). Wave v owns 4 h-units
// [16w+4v .. +4) end-to-end: lane l = (kc=l>>4, r=l&15), gate q=r>>2,
// unit u=r&3, gate row grow = q*512 + 16w + 4v + u, k-chunk [128kc..+128).
// Weights: 32 float4/lane in VGPRs (pinned via asm; load order permuted to
// the staggered LDS layout). Per step: wave v polls chunk v of the tagged
// h-slots (2 u64/lane, data+tag in one packet -> no fences), stages it into
// stg[t&1] (chunk stride 148 floats; group kc reads start at float 4kc ->
// banks {0,24,16,8}+4i, conflict-free; first 48 B duplicated for wrap);
// ONE barrier; matvec (128 FMA, weights from VGPRs); k-reduce via 2
// shfl_xor; activation + i/f/g/o gather via shfl; each wave publishes its
// own 4 units (lanes<4, one 8B atomic exchange carrying {tag,value}).
// Double-buffered staging is race-free: passing barrier(t+1) collectively
// implies every wave finished its step-t reads of stg[t&1].
// ---------------------------------------------------------------------------
__global__ __launch_bounds__(256, 1)
void word_lstm_seq(const float* __restrict__ Whh, const float* __restrict__ Gx,
                   float* __restrict__ hs, u64* hbuf)
{
  __shared__ __align__(16) float stg[2][640];   // [parity][4 chunks x 148 + pad]
  const int tid  = threadIdx.x;
  const int wg   = blockIdx.x;
  const int wv   = tid >> 6;
  const int lane = tid & 63;
  const int kc   = lane >> 4;
  const int r    = lane & 15;
  const int q    = r >> 2;
  const int u    = r & 3;
  const int grow = q * WHID + wg * 16 + wv * 4 + u;   // this lane's gate row

  // weight fragment -> VGPRs, order-permuted to the staggered LDS read layout
  float4 w_[32];
  {
    const float* wsrc = Whh + (size_t)grow * WHID + 128 * kc;
#pragma unroll
    for (int i = 0; i < 32; ++i) {
      const int fo = (4 * kc + 4 * i) & 127;
      w_[i] = *(const float4*)(wsrc + fo);
    }
#pragma unroll
    for (int i = 0; i < 32; ++i)
      asm volatile("" : "+v"(w_[i].x), "+v"(w_[i].y), "+v"(w_[i].z), "+v"(w_[i].w));
  }

  float c_state = 0.f;   // cell state of unit (16wg+4wv+u), replicated x16 lanes

  for (int t = 0; t < S_LEN; ++t) {
    const int par = t & 1;
    float gxv = Gx[(size_t)t * GDIM + grow];  // issue before poll; latency hides
    // ---- poll own chunk (wave wv owns h[128wv..128wv+128), 2 slots/lane) ----
    float v0, v1;
    if (t > 0) {
      const u64* pb = hbuf + (size_t)par * WHID + 128 * wv + 2 * lane;
      const unsigned want = (unsigned)t;
      u64 a, b;
      do {
        a = __hip_atomic_load(pb + 0, __ATOMIC_RELAXED, __HIP_MEMORY_SCOPE_AGENT);
        b = __hip_atomic_load(pb + 1, __ATOMIC_RELAXED, __HIP_MEMORY_SCOPE_AGENT);
      } while (((unsigned)(a >> 32) != want) | ((unsigned)(b >> 32) != want));
      v0 = __uint_as_float((unsigned)a);
      v1 = __uint_as_float((unsigned)b);
    } else { v0 = 0.f; v1 = 0.f; }
    // ---- stage chunk wv (+ dup of first 48 B for staggered wrap) ----
    {
      float* cb = &stg[par][148 * wv];
      *(float2*)(cb + 2 * lane) = make_float2(v0, v1);
      if (lane < 6) *(float2*)(cb + 128 + 2 * lane) = make_float2(v0, v1);
    }
    __syncthreads();   // the ONLY barrier per step
    // ---- matvec: staggered conflict-free LDS reads, weights from VGPRs ----
    const float* rdp = &stg[par][152 * kc];   // 148*kc chunk base + 4*kc stagger
    float acc = 0.f;
#pragma unroll
    for (int i = 0; i < 32; ++i) {
      const float4 hv = *(const float4*)(rdp + 4 * i);
      acc = fmaf(w_[i].x, hv.x, acc);
      acc = fmaf(w_[i].y, hv.y, acc);
      acc = fmaf(w_[i].z, hv.z, acc);
      acc = fmaf(w_[i].w, hv.w, acc);
    }
    // k-reduction across the 4 kc groups (lane bits 4-5)
    acc += __shfl_xor(acc, 16);
    acc += __shfl_xor(acc, 32);
    const float s = acc + gxv;
    // activation per gate row (q==2 is g -> tanh; else sigmoid)
    const float act = (q == 2) ? tanhf_(s) : sigmoidf_(s);
    // gather i,f,g,o of unit u from rows u, 4+u, 8+u, 12+u (same kc group)
    const int gb = lane & 48;
    const float iv = __shfl(act, gb + u);
    const float fv = __shfl(act, gb + 4 + u);
    const float gv = __shfl(act, gb + 8 + u);
    const float ov = __shfl(act, gb + 12 + u);
    c_state = fv * c_state + iv * gv;
    const float hv = ov * tanhf_(c_state);
    if (lane < 4) {   // kc=0, u=lane: publish this wave's 4 units
      const int hidx = wg * 16 + wv * 4 + lane;
      const u64 pkt = ((u64)(unsigned)(t + 1) << 32) | (u64)__float_as_uint(hv);
      (void)__hip_atomic_exchange(&hbuf[(size_t)((t + 1) & 1) * WHID + hidx], pkt,
                                  __ATOMIC_RELAXED, __HIP_MEMORY_SCOPE_AGENT);
      hs[(size_t)t * WHID + hidx] = hv;
    }
  }
}

// ---------------------------------------------------------------------------
// K4: logits + log_softmax. One 64-lane wave per row t; lane = tag.
// ---------------------------------------------------------------------------
__global__ __launch_bounds__(256)
void tag_kernel(const float* __restrict__ hs, const float* __restrict__ W,
                const float* __restrict__ b, float* __restrict__ out)
{
  const int wave = threadIdx.x >> 6;
  const int lane = threadIdx.x & 63;
  const int t = blockIdx.x * 4 + wave;
  const float* hr = hs + (size_t)t * WHID;
  const float* wr = W + (size_t)lane * WHID;
  float acc = b[lane];
  for (int k = 0; k < WHID; k += 4) {
    float4 wv = *(const float4*)(wr + k);
    float4 hv = *(const float4*)(hr + k);
    acc = fmaf(wv.x, hv.x, acc);
    acc = fmaf(wv.y, hv.y, acc);
    acc = fmaf(wv.z, hv.z, acc);
    acc = fmaf(wv.w, hv.w, acc);
  }
  float m = acc;
#pragma unroll
  for (int off = 32; off > 0; off >>= 1) m = fmaxf(m, __shfl_xor(m, off));
  float e = __expf(acc - m);
  float sum = e;
#pragma unroll
  for (int off = 32; off > 0; off >>= 1) sum += __shfl_xor(sum, off);
  out[(size_t)t * NTAG + lane] = (acc - m) - __logf(sum);
}

extern "C" void kernel_launch(void* const* d_in, const int* in_sizes, int n_in,
                              void* d_out, int out_size, void* d_ws, size_t ws_size,
                              hipStream_t stream)
{
  const int* x          = (const int*)d_in[0];
  const int* chars      = (const int*)d_in[1];
  const int* lengths    = (const int*)d_in[2];
  const float* word_emb = (const float*)d_in[3];
  const float* char_emb = (const float*)d_in[4];
  const float* c_Wih    = (const float*)d_in[5];
  const float* c_Whh    = (const float*)d_in[6];
  const float* c_bih    = (const float*)d_in[7];
  const float* c_bhh    = (const float*)d_in[8];
  const float* w_Wih    = (const float*)d_in[9];
  const float* w_Whh    = (const float*)d_in[10];
  const float* w_bih    = (const float*)d_in[11];
  const float* w_bhh    = (const float*)d_in[12];
  const float* lin_W    = (const float*)d_in[13];
  const float* lin_b    = (const float*)d_in[14];
  float* out = (float*)d_out;

  char* ws = (char*)d_ws;
  // layout: [0,8192) hbuf (2 x 512 u64 tagged slots) |
  //         char_feat 4 MiB | Gx 64 MiB | hs 16 MiB   (total ~84 MiB)
  u64*   hbuf      = (u64*)ws;
  float* char_feat = (float*)(ws + 8192);
  float* Gx        = (float*)(ws + 8192 + (size_t)S_LEN * CHID * 4);
  float* hs        = (float*)(ws + 8192 + (size_t)S_LEN * CHID * 4
                                        + (size_t)S_LEN * GDIM * 4);

  // zero tags every call (tag 0 never matches an expected epoch t >= 1)
  hipMemsetAsync(ws, 0, 8192, stream);

  char_lstm_kernel<<<S_LEN / 16, 256, 0, stream>>>(
      chars, lengths, char_emb, c_Wih, c_Whh, c_bih, c_bhh, char_feat);

  dim3 g2(GDIM / BN, S_LEN / BM);
  gx_gemm_kernel<<<g2, 256, 0, stream>>>(
      x, word_emb, char_feat, w_Wih, w_bih, w_bhh, Gx);

  word_lstm_seq<<<NWG, 256, 0, stream>>>(w_Whh, Gx, hs, hbuf);

  tag_kernel<<<S_LEN / 4, 256, 0, stream>>>(hs, lin_W, lin_b, out);
}

// Round 6
// 17904.932 us; speedup vs baseline: 1.1057x; 1.1057x over previous
//
#include <hip/hip_runtime.h>
#include <hip/hip_bf16.h>

#define S_LEN 8192
#define CLEN 16
#define WDIM 256
#define CDIM 64
#define CHID 128
#define WHID 512
#define GDIM 2048   // 4*WHID
#define NTAG 64
#define KDIM 384    // WDIM + CHID
#define NWG 32      // workgroups per sequential group (backbone or replica)

typedef unsigned long long u64;

__device__ __forceinline__ float sigmoidf_(float x) {
  return 1.0f / (1.0f + __expf(-x));
}
__device__ __forceinline__ float tanhf_(float x) {
  // safe tanh: 1 - 2/(e^{2x}+1); correct limits at +-inf without NaN
  return 1.0f - 2.0f / (__expf(2.0f * x) + 1.0f);
}

// ---------------------------------------------------------------------------
// K1: batched char LSTM. 16 words per block (two groups of 8), 256 threads.
// ---------------------------------------------------------------------------
__global__ __launch_bounds__(256)
void char_lstm_kernel(const int* __restrict__ chars, const int* __restrict__ lengths,
                      const float* __restrict__ emb, const float* __restrict__ Wih,
                      const float* __restrict__ Whh, const float* __restrict__ bih,
                      const float* __restrict__ bhh, float* __restrict__ cf)
{
  __shared__ float xs[16][CDIM];
  __shared__ float hsm[16][CHID];
  __shared__ int cidx[16];
  __shared__ int lens[16];
  const int tid = threadIdx.x;
  const int grp = tid >> 7;      // 0..1 (word group)
  const int j = tid & 127;       // hidden index
  const int wb = blockIdx.x * 16;

  for (int i = tid; i < 16 * CHID; i += 256) (&hsm[0][0])[i] = 0.f;
  if (tid < 16) lens[tid] = lengths[wb + tid];
  float c[8];
#pragma unroll
  for (int w = 0; w < 8; ++w) c[w] = 0.f;
  const float bi = bih[j] + bhh[j];
  const float bf = bih[CHID + j] + bhh[CHID + j];
  const float bg = bih[2 * CHID + j] + bhh[2 * CHID + j];
  const float bo = bih[3 * CHID + j] + bhh[3 * CHID + j];

  for (int t = 0; t < CLEN; ++t) {
    __syncthreads();
    if (tid < 16) cidx[tid] = chars[(wb + tid) * CLEN + t];
    __syncthreads();
    {
      int e = tid * 4;
      int wi = e >> 6;
      int k = e & 63;
      const float4 v = *(const float4*)(emb + (size_t)cidx[wi] * CDIM + k);
      *(float4*)(&xs[wi][k]) = v;
    }
    __syncthreads();
    float ai[8], af[8], ag[8], ao[8];
#pragma unroll
    for (int w = 0; w < 8; ++w) { ai[w] = bi; af[w] = bf; ag[w] = bg; ao[w] = bo; }
    // x part (K = 64)
    for (int k = 0; k < CDIM; k += 4) {
      float4 w0 = *(const float4*)(Wih + (size_t)j * CDIM + k);
      float4 w1 = *(const float4*)(Wih + (size_t)(CHID + j) * CDIM + k);
      float4 w2 = *(const float4*)(Wih + (size_t)(2 * CHID + j) * CDIM + k);
      float4 w3 = *(const float4*)(Wih + (size_t)(3 * CHID + j) * CDIM + k);
#pragma unroll
      for (int s = 0; s < 4; ++s) {
        float wiv = (&w0.x)[s], wfv = (&w1.x)[s], wgv = (&w2.x)[s], wov = (&w3.x)[s];
#pragma unroll
        for (int w = 0; w < 8; ++w) {
          float xv = xs[grp * 8 + w][k + s];   // wave-uniform -> LDS broadcast
          ai[w] = fmaf(wiv, xv, ai[w]);
          af[w] = fmaf(wfv, xv, af[w]);
          ag[w] = fmaf(wgv, xv, ag[w]);
          ao[w] = fmaf(wov, xv, ao[w]);
        }
      }
    }
    // h part (K = 128)
    for (int k = 0; k < CHID; k += 4) {
      float4 w0 = *(const float4*)(Whh + (size_t)j * CHID + k);
      float4 w1 = *(const float4*)(Whh + (size_t)(CHID + j) * CHID + k);
      float4 w2 = *(const float4*)(Whh + (size_t)(2 * CHID + j) * CHID + k);
      float4 w3 = *(const float4*)(Whh + (size_t)(3 * CHID + j) * CHID + k);
#pragma unroll
      for (int s = 0; s < 4; ++s) {
        float wiv = (&w0.x)[s], wfv = (&w1.x)[s], wgv = (&w2.x)[s], wov = (&w3.x)[s];
#pragma unroll
        for (int w = 0; w < 8; ++w) {
          float hv = hsm[grp * 8 + w][k + s];
          ai[w] = fmaf(wiv, hv, ai[w]);
          af[w] = fmaf(wfv, hv, af[w]);
          ag[w] = fmaf(wgv, hv, ag[w]);
          ao[w] = fmaf(wov, hv, ao[w]);
        }
      }
    }
    __syncthreads();
#pragma unroll
    for (int w = 0; w < 8; ++w) {
      if (t < lens[grp * 8 + w]) {
        float iv = sigmoidf_(ai[w]);
        float fv = sigmoidf_(af[w]);
        float gv = tanhf_(ag[w]);
        float ov = sigmoidf_(ao[w]);
        c[w] = fv * c[w] + iv * gv;
        hsm[grp * 8 + w][j] = ov * tanhf_(c[w]);
      }
    }
  }
#pragma unroll
  for (int w = 0; w < 8; ++w)
    cf[(size_t)(wb + grp * 8 + w) * CHID + j] = c[w];   // feature = final CELL state
}

// ---------------------------------------------------------------------------
// K2: G_x[t][g] = [word_emb[x[t]] | char_feat[t]] @ w_Wih^T + (bih+bhh)
// ---------------------------------------------------------------------------
#define BM 64
#define BN 64
#define BK 32
__global__ __launch_bounds__(256)
void gx_gemm_kernel(const int* __restrict__ x, const float* __restrict__ word_emb,
                    const float* __restrict__ char_feat, const float* __restrict__ Wih,
                    const float* __restrict__ bih, const float* __restrict__ bhh,
                    float* __restrict__ Gx)
{
  __shared__ float As[BK][BM + 1];
  __shared__ float Bs[BK][BN + 1];
  __shared__ int xidx[BM];
  const int tid = threadIdx.x;
  const int tx = tid & 15, ty = tid >> 4;
  const int m0 = blockIdx.y * BM;
  const int n0 = blockIdx.x * BN;
  if (tid < BM) xidx[tid] = x[m0 + tid];
  float acc[4][4] = {};
  for (int k0 = 0; k0 < KDIM; k0 += BK) {
    __syncthreads();
    {
      int i = tid >> 5;
      int kk = tid & 31;
#pragma unroll
      for (int l = 0; l < 8; ++l) {
        int row = i + l * 8;
        int k = k0 + kk;
        int tt = m0 + row;
        float v = (k < WDIM) ? word_emb[(size_t)xidx[row] * WDIM + k]
                             : char_feat[(size_t)tt * CHID + (k - WDIM)];
        As[kk][row] = v;
      }
    }
    {
      int jjj = tid >> 5;
      int kk = tid & 31;
#pragma unroll
      for (int l = 0; l < 8; ++l) {
        int col = jjj + l * 8;
        Bs[kk][col] = Wih[(size_t)(n0 + col) * KDIM + k0 + kk];
      }
    }
    __syncthreads();
#pragma unroll
    for (int kk = 0; kk < BK; ++kk) {
      float a[4], b[4];
#pragma unroll
      for (int m = 0; m < 4; ++m) a[m] = As[kk][ty * 4 + m];
#pragma unroll
      for (int n = 0; n < 4; ++n) b[n] = Bs[kk][tx * 4 + n];
#pragma unroll
      for (int m = 0; m < 4; ++m)
#pragma unroll
        for (int n = 0; n < 4; ++n)
          acc[m][n] = fmaf(a[m], b[n], acc[m][n]);
    }
  }
#pragma unroll
  for (int n = 0; n < 4; ++n) {
    int g = n0 + tx * 4 + n;
    float bias = bih[g] + bhh[g];
#pragma unroll
    for (int m = 0; m < 4; ++m) {
      int tt = m0 + ty * 4 + m;
      Gx[(size_t)tt * GDIM + g] = acc[m][n] + bias;
    }
  }
}

// ---------------------------------------------------------------------------
// K3: sequential word LSTM, v6: backbone + XCD-local replicas, provable
// termination.
//
// Blocks 0..31 = BACKBONE: exactly the round-3 agent-scope tagged-slot scheme
// on hbufG (sole mirror writer -> tags monotone, never clobbered). Blocks
// 32..319 = candidates: ticket per HW_REG_XCC_ID; tickets 0..31 of a complete
// group (bounded formation spin, else exit) run the SAME code as a replica,
// publishing wg-scope atomics (local-L2) to a private per-XCD buffer and
// polling it with sc0 loads (L1-bypass, local-L2 service). Fallback for any
// replica lane: poll backbone's mirror (always live). ALL unbounded waits
// check a global `done` flag every 16 iters. First group to finish all 8192
// steps sets done; everyone else bails (skipping publish/hs on the bailed
// step). All groups compute bit-identical f32 -> duplicate hs writes benign.
// Worst case (no replica forms) == backbone == round-3 performance.
//
// Weights per WG (64 rows x 512 = 128 KB): half LDS-resident (k 0..63 of each
// 128-chunk, transposed wlds[g][cc*64+lane] -> lane-consecutive ds_read_b128,
// conflict-free; 64 KB keeps 2 blocks/CU so all 320 blocks stay resident),
// half in 16 named float4 (compiler may hold in VGPR or re-fetch from L2 --
// both fine; replica L2 re-fetch is 2 MB/step/XCD, within local L2 BW).
// ---------------------------------------------------------------------------
__global__ __launch_bounds__(256, 1)
void word_lstm_seq(const float* __restrict__ Whh, const float* __restrict__ Gx,
                   float* __restrict__ hs, u64* hbufG, u64* hbufL,
                   int* tickets, int* done_cnt, int* done)
{
  __shared__ __align__(16) float4 wlds[4096];   // 64 KiB LDS weight half
  __shared__ float h_lds[WHID];
  __shared__ float red[2][256];
  __shared__ int wg_s, loc_s, bail_s;
  const int tid = threadIdx.x;
  const int bid = blockIdx.x;

  // ---- role resolution ----
  if (tid == 0) {
    bail_s = 0;
    int myid, loc;
    if (bid < NWG) {            // backbone: always present, agent-scope
      myid = bid; loc = -1;
    } else {                    // candidate: try to join this XCD's replica
      unsigned xcc;
      asm volatile("s_getreg_b32 %0, hwreg(HW_REG_XCC_ID)" : "=s"(xcc));
      xcc &= 15u;
      int tk = __hip_atomic_fetch_add(&tickets[xcc], 1, __ATOMIC_RELAXED,
                                      __HIP_MEMORY_SCOPE_AGENT);
      myid = -1; loc = (int)xcc;
      if (tk < NWG) {
        for (int i = 0; i < 30000; ++i) {   // bounded formation wait
          if (__hip_atomic_load(&tickets[xcc], __ATOMIC_RELAXED,
                                __HIP_MEMORY_SCOPE_AGENT) >= NWG) {
            myid = tk; break;
          }
        }
      }
    }
    wg_s = myid; loc_s = loc;
  }
  __syncthreads();
  const int wg = wg_s;
  if (wg < 0) return;                       // extra / orphaned candidates exit
  const bool local = (loc_s >= 0);
  u64* __restrict__ mybuf = local ? (hbufL + (size_t)loc_s * 1024) : hbufG;

  const int cc   = tid >> 6;      // k-chunk 0..3
  const int lane = tid & 63;      // gate row within WG slice
  const int kb   = cc * 128;
  const int grow = (lane >> 4) * WHID + wg * 16 + (lane & 15);

  // ---- stage LDS weight half: k in [c2*128, c2*128+64), transposed ----
  for (int L = tid; L < 4096; L += 256) {
    int g = L >> 8;               // 0..15 -> k offset 4g
    int rem = L & 255;
    int c2 = rem >> 6;
    int r = rem & 63;
    int gr = (r >> 4) * WHID + wg * 16 + (r & 15);
    wlds[L] = *(const float4*)(Whh + (size_t)gr * WHID + c2 * 128 + 4 * g);
  }
  // register/L2 half: k in [kb+64, kb+128)
  float4 wr_[16];
  {
    const float* wsrc2 = Whh + (size_t)grow * WHID + kb + 64;
#pragma unroll
    for (int i = 0; i < 16; ++i) wr_[i] = *(const float4*)(wsrc2 + 4 * i);
  }
  __syncthreads();

  float c_state = 0.f;            // lanes<16 of wave 0 use
  int lmode = local ? 1 : 0;      // replica lanes start optimistic-local

  for (int t = 0; t < S_LEN; ++t) {
    const int par = t & 1;
    float gxv = 0.f;
    if (tid < 64)
      gxv = Gx[(size_t)t * GDIM + grow];   // issued before poll; latency hides
    // ---- poll own 2 tagged slots {lo32=value, hi32=tag} ----
    float v0 = 0.f, v1 = 0.f;
    if (t > 0) {
      const unsigned want = (unsigned)t;
      const size_t soff = (size_t)par * WHID + kb + 2 * lane;
      bool found = false;
      if (lmode) {                          // replica fast path: local L2
        const u64* pL = mybuf + soff;
        int iter = 0;
        for (;;) {
          int4 rr;
          asm volatile("global_load_dwordx4 %0, %1, off sc0\n\t"
                       "s_waitcnt vmcnt(0)"
                       : "=v"(rr) : "v"(pL) : "memory");
          if ((unsigned)rr.y == want && (unsigned)rr.w == want) {
            v0 = __int_as_float(rr.x); v1 = __int_as_float(rr.z);
            found = true; break;
          }
          ++iter;
          if (t == 1 && iter >= 4096) { lmode = 0; break; }  // latch off
          if ((iter & 15) == 0 &&
              __hip_atomic_load(done, __ATOMIC_RELAXED,
                                __HIP_MEMORY_SCOPE_AGENT)) {
            bail_s = 1; found = true; break;   // garbage; bail after barrier
          }
        }
      }
      if (!found) {                         // backbone path / replica fallback
        const u64* pG = hbufG + soff;
        const u64* pL = mybuf + soff;
        int iter = 0;
        for (;;) {
          u64 a = __hip_atomic_load(pG + 0, __ATOMIC_RELAXED,
                                    __HIP_MEMORY_SCOPE_AGENT);
          u64 b = __hip_atomic_load(pG + 1, __ATOMIC_RELAXED,
                                    __HIP_MEMORY_SCOPE_AGENT);
          if ((unsigned)(a >> 32) == want && (unsigned)(b >> 32) == want) {
            v0 = __uint_as_float((unsigned)a);
            v1 = __uint_as_float((unsigned)b);
            break;
          }
          if (local) {                      // also try local while falling back
            int4 rr;
            asm volatile("global_load_dwordx4 %0, %1, off sc0\n\t"
                         "s_waitcnt vmcnt(0)"
                         : "=v"(rr) : "v"(pL) : "memory");
            if ((unsigned)rr.y == want && (unsigned)rr.w == want) {
              v0 = __int_as_float(rr.x); v1 = __int_as_float(rr.z); break;
            }
          }
          if (((++iter) & 15) == 0 &&
              __hip_atomic_load(done, __ATOMIC_RELAXED,
                                __HIP_MEMORY_SCOPE_AGENT)) {
            bail_s = 1; break;
          }
        }
      }
    }
    // ---- stage own chunk (wave-private LDS region) ----
    *(float2*)(&h_lds[kb + 2 * lane]) = make_float2(v0, v1);
    __threadfence_block();
    // ---- matvec: LDS half then reg/L2 half; h broadcast from LDS ----
    float acc = 0.f;
#pragma unroll
    for (int g = 0; g < 16; ++g) {
      const float4 wv = wlds[g * 256 + cc * 64 + lane];
      const float4 hv = *(const float4*)(&h_lds[kb + 4 * g]);
      acc = fmaf(wv.x, hv.x, acc);
      acc = fmaf(wv.y, hv.y, acc);
      acc = fmaf(wv.z, hv.z, acc);
      acc = fmaf(wv.w, hv.w, acc);
    }
#pragma unroll
    for (int i = 0; i < 16; ++i) {
      const float4 hv = *(const float4*)(&h_lds[kb + 64 + 4 * i]);
      acc = fmaf(wr_[i].x, hv.x, acc);
      acc = fmaf(wr_[i].y, hv.y, acc);
      acc = fmaf(wr_[i].z, hv.z, acc);
      acc = fmaf(wr_[i].w, hv.w, acc);
    }
    red[par][tid] = acc;
    __syncthreads();   // the ONLY barrier per step
    if (bail_s) break; // someone finished the whole problem -> exit early
    if (tid < 64) {
      const float* rp = red[par];
      float s = rp[lane] + rp[64 + lane] + rp[128 + lane] + rp[192 + lane] + gxv;
      float act = ((lane >> 4) == 2) ? tanhf_(s) : sigmoidf_(s);
      int jj = lane & 15;
      float iv = __shfl(act, jj);
      float fv = __shfl(act, 16 + jj);
      float gv = __shfl(act, 32 + jj);
      float ov = __shfl(act, 48 + jj);
      if (lane < 16) {
        c_state = fv * c_state + iv * gv;
        float hv = ov * tanhf_(c_state);
        const int hidx = wg * 16 + lane;
        const u64 pkt = ((u64)(unsigned)(t + 1) << 32) | (u64)__float_as_uint(hv);
        const size_t off = (size_t)((t + 1) & 1) * WHID + hidx;
        if (local)   // wg-scope RMW executes at this XCD's L2 (fast path)
          (void)__hip_atomic_exchange(mybuf + off, pkt, __ATOMIC_RELAXED,
                                      __HIP_MEMORY_SCOPE_WORKGROUP);
        else         // backbone: agent RMW at coherence point (mirror)
          (void)__hip_atomic_exchange(mybuf + off, pkt, __ATOMIC_RELAXED,
                                      __HIP_MEMORY_SCOPE_AGENT);
        hs[(size_t)t * WHID + hidx] = hv;  // duplicate same-value stores OK
      }
    }
  }

  // ---- completion protocol: first full group releases everyone ----
  if (tid == 0 && !bail_s) {
    const int gidx = local ? loc_s : 16;
    int r = __hip_atomic_fetch_add(&done_cnt[gidx], 1, __ATOMIC_RELAXED,
                                   __HIP_MEMORY_SCOPE_AGENT);
    if (r == NWG - 1)
      __hip_atomic_store(done, 1, __ATOMIC_RELEASE, __HIP_MEMORY_SCOPE_AGENT);
  }
}

// ---------------------------------------------------------------------------
// K4: logits + log_softmax. One 64-lane wave per row t; lane = tag.
// ---------------------------------------------------------------------------
__global__ __launch_bounds__(256)
void tag_kernel(const float* __restrict__ hs, const float* __restrict__ W,
                const float* __restrict__ b, float* __restrict__ out)
{
  const int wave = threadIdx.x >> 6;
  const int lane = threadIdx.x & 63;
  const int t = blockIdx.x * 4 + wave;
  const float* hr = hs + (size_t)t * WHID;
  const float* wr = W + (size_t)lane * WHID;
  float acc = b[lane];
  for (int k = 0; k < WHID; k += 4) {
    float4 wv = *(const float4*)(wr + k);
    float4 hv = *(const float4*)(hr + k);
    acc = fmaf(wv.x, hv.x, acc);
    acc = fmaf(wv.y, hv.y, acc);
    acc = fmaf(wv.z, hv.z, acc);
    acc = fmaf(wv.w, hv.w, acc);
  }
  float m = acc;
#pragma unroll
  for (int off = 32; off > 0; off >>= 1) m = fmaxf(m, __shfl_xor(m, off));
  float e = __expf(acc - m);
  float sum = e;
#pragma unroll
  for (int off = 32; off > 0; off >>= 1) sum += __shfl_xor(sum, off);
  out[(size_t)t * NTAG + lane] = (acc - m) - __logf(sum);
}

extern "C" void kernel_launch(void* const* d_in, const int* in_sizes, int n_in,
                              void* d_out, int out_size, void* d_ws, size_t ws_size,
                              hipStream_t stream)
{
  const int* x          = (const int*)d_in[0];
  const int* chars      = (const int*)d_in[1];
  const int* lengths    = (const int*)d_in[2];
  const float* word_emb = (const float*)d_in[3];
  const float* char_emb = (const float*)d_in[4];
  const float* c_Wih    = (const float*)d_in[5];
  const float* c_Whh    = (const float*)d_in[6];
  const float* c_bih    = (const float*)d_in[7];
  const float* c_bhh    = (const float*)d_in[8];
  const float* w_Wih    = (const float*)d_in[9];
  const float* w_Whh    = (const float*)d_in[10];
  const float* w_bih    = (const float*)d_in[11];
  const float* w_bhh    = (const float*)d_in[12];
  const float* lin_W    = (const float*)d_in[13];
  const float* lin_b    = (const float*)d_in[14];
  float* out = (float*)d_out;

  char* ws = (char*)d_ws;
  // layout: [0,64) tickets[16] | [64,132) done_cnt[17] | [132,136) done |
  //         [4096,12288) hbufG (2x512 u64) | [16384,147456) hbufL (16x1024 u64)
  //         | char_feat 4MiB | Gx 64MiB | hs 16MiB      (total ~84.2 MiB)
  int*   tickets   = (int*)ws;
  int*   done_cnt  = (int*)(ws + 64);
  int*   done      = (int*)(ws + 132);
  u64*   hbufG     = (u64*)(ws + 4096);
  u64*   hbufL     = (u64*)(ws + 16384);
  float* char_feat = (float*)(ws + 147456);
  float* Gx        = (float*)(ws + 147456 + (size_t)S_LEN * CHID * 4);
  float* hs        = (float*)(ws + 147456 + (size_t)S_LEN * CHID * 4
                                          + (size_t)S_LEN * GDIM * 4);

  // zero control block + all tagged-slot buffers every call (replay-safe)
  hipMemsetAsync(ws, 0, 147456, stream);

  char_lstm_kernel<<<S_LEN / 16, 256, 0, stream>>>(
      chars, lengths, char_emb, c_Wih, c_Whh, c_bih, c_bhh, char_feat);

  dim3 g2(GDIM / BN, S_LEN / BM);
  gx_gemm_kernel<<<g2, 256, 0, stream>>>(
      x, word_emb, char_feat, w_Wih, w_bih, w_bhh, Gx);

  word_lstm_seq<<<320, 256, 0, stream>>>(w_Whh, Gx, hs, hbufG, hbufL,
                                         tickets, done_cnt, done);

  tag_kernel<<<S_LEN / 4, 256, 0, stream>>>(hs, lin_W, lin_b, out);
}

// Round 7
// 17776.529 us; speedup vs baseline: 1.1136x; 1.0072x over previous
//
#include <hip/hip_runtime.h>
#include <hip/hip_bf16.h>

#define S_LEN 8192
#define CLEN 16
#define WDIM 256
#define CDIM 64
#define CHID 128
#define WHID 512
#define GDIM 2048   // 4*WHID
#define NTAG 64
#define KDIM 384    // WDIM + CHID
#define NWG 32      // workgroups per sequential group (backbone or replica)

typedef unsigned long long u64;

__device__ __forceinline__ float sigmoidf_(float x) {
  return 1.0f / (1.0f + __expf(-x));
}
__device__ __forceinline__ float tanhf_(float x) {
  // safe tanh: 1 - 2/(e^{2x}+1); correct limits at +-inf without NaN
  return 1.0f - 2.0f / (__expf(2.0f * x) + 1.0f);
}

// ---------------------------------------------------------------------------
// K1: batched char LSTM. 16 words per block (two groups of 8), 256 threads.
// ---------------------------------------------------------------------------
__global__ __launch_bounds__(256)
void char_lstm_kernel(const int* __restrict__ chars, const int* __restrict__ lengths,
                      const float* __restrict__ emb, const float* __restrict__ Wih,
                      const float* __restrict__ Whh, const float* __restrict__ bih,
                      const float* __restrict__ bhh, float* __restrict__ cf)
{
  __shared__ float xs[16][CDIM];
  __shared__ float hsm[16][CHID];
  __shared__ int cidx[16];
  __shared__ int lens[16];
  const int tid = threadIdx.x;
  const int grp = tid >> 7;      // 0..1 (word group)
  const int j = tid & 127;       // hidden index
  const int wb = blockIdx.x * 16;

  for (int i = tid; i < 16 * CHID; i += 256) (&hsm[0][0])[i] = 0.f;
  if (tid < 16) lens[tid] = lengths[wb + tid];
  float c[8];
#pragma unroll
  for (int w = 0; w < 8; ++w) c[w] = 0.f;
  const float bi = bih[j] + bhh[j];
  const float bf = bih[CHID + j] + bhh[CHID + j];
  const float bg = bih[2 * CHID + j] + bhh[2 * CHID + j];
  const float bo = bih[3 * CHID + j] + bhh[3 * CHID + j];

  for (int t = 0; t < CLEN; ++t) {
    __syncthreads();
    if (tid < 16) cidx[tid] = chars[(wb + tid) * CLEN + t];
    __syncthreads();
    {
      int e = tid * 4;
      int wi = e >> 6;
      int k = e & 63;
      const float4 v = *(const float4*)(emb + (size_t)cidx[wi] * CDIM + k);
      *(float4*)(&xs[wi][k]) = v;
    }
    __syncthreads();
    float ai[8], af[8], ag[8], ao[8];
#pragma unroll
    for (int w = 0; w < 8; ++w) { ai[w] = bi; af[w] = bf; ag[w] = bg; ao[w] = bo; }
    // x part (K = 64)
    for (int k = 0; k < CDIM; k += 4) {
      float4 w0 = *(const float4*)(Wih + (size_t)j * CDIM + k);
      float4 w1 = *(const float4*)(Wih + (size_t)(CHID + j) * CDIM + k);
      float4 w2 = *(const float4*)(Wih + (size_t)(2 * CHID + j) * CDIM + k);
      float4 w3 = *(const float4*)(Wih + (size_t)(3 * CHID + j) * CDIM + k);
#pragma unroll
      for (int s = 0; s < 4; ++s) {
        float wiv = (&w0.x)[s], wfv = (&w1.x)[s], wgv = (&w2.x)[s], wov = (&w3.x)[s];
#pragma unroll
        for (int w = 0; w < 8; ++w) {
          float xv = xs[grp * 8 + w][k + s];   // wave-uniform -> LDS broadcast
          ai[w] = fmaf(wiv, xv, ai[w]);
          af[w] = fmaf(wfv, xv, af[w]);
          ag[w] = fmaf(wgv, xv, ag[w]);
          ao[w] = fmaf(wov, xv, ao[w]);
        }
      }
    }
    // h part (K = 128)
    for (int k = 0; k < CHID; k += 4) {
      float4 w0 = *(const float4*)(Whh + (size_t)j * CHID + k);
      float4 w1 = *(const float4*)(Whh + (size_t)(CHID + j) * CHID + k);
      float4 w2 = *(const float4*)(Whh + (size_t)(2 * CHID + j) * CHID + k);
      float4 w3 = *(const float4*)(Whh + (size_t)(3 * CHID + j) * CHID + k);
#pragma unroll
      for (int s = 0; s < 4; ++s) {
        float wiv = (&w0.x)[s], wfv = (&w1.x)[s], wgv = (&w2.x)[s], wov = (&w3.x)[s];
#pragma unroll
        for (int w = 0; w < 8; ++w) {
          float hv = hsm[grp * 8 + w][k + s];
          ai[w] = fmaf(wiv, hv, ai[w]);
          af[w] = fmaf(wfv, hv, af[w]);
          ag[w] = fmaf(wgv, hv, ag[w]);
          ao[w] = fmaf(wov, hv, ao[w]);
        }
      }
    }
    __syncthreads();
#pragma unroll
    for (int w = 0; w < 8; ++w) {
      if (t < lens[grp * 8 + w]) {
        float iv = sigmoidf_(ai[w]);
        float fv = sigmoidf_(af[w]);
        float gv = tanhf_(ag[w]);
        float ov = sigmoidf_(ao[w]);
        c[w] = fv * c[w] + iv * gv;
        hsm[grp * 8 + w][j] = ov * tanhf_(c[w]);
      }
    }
  }
#pragma unroll
  for (int w = 0; w < 8; ++w)
    cf[(size_t)(wb + grp * 8 + w) * CHID + j] = c[w];   // feature = final CELL state
}

// ---------------------------------------------------------------------------
// K2: G_x[t][g] = [word_emb[x[t]] | char_feat[t]] @ w_Wih^T + (bih+bhh)
// ---------------------------------------------------------------------------
#define BM 64
#define BN 64
#define BK 32
__global__ __launch_bounds__(256)
void gx_gemm_kernel(const int* __restrict__ x, const float* __restrict__ word_emb,
                    const float* __restrict__ char_feat, const float* __restrict__ Wih,
                    const float* __restrict__ bih, const float* __restrict__ bhh,
                    float* __restrict__ Gx)
{
  __shared__ float As[BK][BM + 1];
  __shared__ float Bs[BK][BN + 1];
  __shared__ int xidx[BM];
  const int tid = threadIdx.x;
  const int tx = tid & 15, ty = tid >> 4;
  const int m0 = blockIdx.y * BM;
  const int n0 = blockIdx.x * BN;
  if (tid < BM) xidx[tid] = x[m0 + tid];
  float acc[4][4] = {};
  for (int k0 = 0; k0 < KDIM; k0 += BK) {
    __syncthreads();
    {
      int i = tid >> 5;
      int kk = tid & 31;
#pragma unroll
      for (int l = 0; l < 8; ++l) {
        int row = i + l * 8;
        int k = k0 + kk;
        int tt = m0 + row;
        float v = (k < WDIM) ? word_emb[(size_t)xidx[row] * WDIM + k]
                             : char_feat[(size_t)tt * CHID + (k - WDIM)];
        As[kk][row] = v;
      }
    }
    {
      int jjj = tid >> 5;
      int kk = tid & 31;
#pragma unroll
      for (int l = 0; l < 8; ++l) {
        int col = jjj + l * 8;
        Bs[kk][col] = Wih[(size_t)(n0 + col) * KDIM + k0 + kk];
      }
    }
    __syncthreads();
#pragma unroll
    for (int kk = 0; kk < BK; ++kk) {
      float a[4], b[4];
#pragma unroll
      for (int m = 0; m < 4; ++m) a[m] = As[kk][ty * 4 + m];
#pragma unroll
      for (int n = 0; n < 4; ++n) b[n] = Bs[kk][tx * 4 + n];
#pragma unroll
      for (int m = 0; m < 4; ++m)
#pragma unroll
        for (int n = 0; n < 4; ++n)
          acc[m][n] = fmaf(a[m], b[n], acc[m][n]);
    }
  }
#pragma unroll
  for (int n = 0; n < 4; ++n) {
    int g = n0 + tx * 4 + n;
    float bias = bih[g] + bhh[g];
#pragma unroll
    for (int m = 0; m < 4; ++m) {
      int tt = m0 + ty * 4 + m;
      Gx[(size_t)tt * GDIM + g] = acc[m][n] + bias;
    }
  }
}

// ---------------------------------------------------------------------------
// K3: sequential word LSTM, v7 = v6 + three fixes:
//  (1) "=&v" early-clobber on ALL asm poll loads (v6's "=v" let the loaded
//      dwordx4 overlap the address pair -> poll address clobbered -> every
//      replica latched to fallback -> hbufG contention -> 15.9 ms).
//  (2) register-half weight loads + Gx issued BEFORE the poll asm; the asm's
//      "memory" clobber pins them there, so their L2 latency hides under the
//      poll wait instead of serializing after it.
//  (3) fallback polls paced with s_sleep so a fallback storm can't throttle
//      the backbone; t==1 latch bound raised to 32768 (still bounded).
// Structure unchanged: blocks 0..31 backbone (agent-scope tagged slots in
// hbufG, sole mirror writer); blocks 32..319 ticket per HW_REG_XCC_ID into
// per-XCD replicas (wg-scope publish to private hbufL slice + sc0 polls =
// XCD-local L2 sync); every unbounded wait checks `done`; first complete
// group sets done, everyone else bails. All groups bit-identical f32.
// ---------------------------------------------------------------------------
__global__ __launch_bounds__(256, 1)
void word_lstm_seq(const float* __restrict__ Whh, const float* __restrict__ Gx,
                   float* __restrict__ hs, u64* hbufG, u64* hbufL,
                   int* tickets, int* done_cnt, int* done)
{
  __shared__ __align__(16) float4 wlds[4096];   // 64 KiB LDS weight half
  __shared__ float h_lds[WHID];
  __shared__ float red[2][256];
  __shared__ int wg_s, loc_s, bail_s;
  const int tid = threadIdx.x;
  const int bid = blockIdx.x;

  // ---- role resolution ----
  if (tid == 0) {
    bail_s = 0;
    int myid, loc;
    if (bid < NWG) {            // backbone: always present, agent-scope
      myid = bid; loc = -1;
    } else {                    // candidate: try to join this XCD's replica
      unsigned xcc;
      asm volatile("s_getreg_b32 %0, hwreg(HW_REG_XCC_ID)" : "=s"(xcc));
      xcc &= 15u;
      int tk = __hip_atomic_fetch_add(&tickets[xcc], 1, __ATOMIC_RELAXED,
                                      __HIP_MEMORY_SCOPE_AGENT);
      myid = -1; loc = (int)xcc;
      if (tk < NWG) {
        for (int i = 0; i < 30000; ++i) {   // bounded formation wait
          if (__hip_atomic_load(&tickets[xcc], __ATOMIC_RELAXED,
                                __HIP_MEMORY_SCOPE_AGENT) >= NWG) {
            myid = tk; break;
          }
        }
      }
    }
    wg_s = myid; loc_s = loc;
  }
  __syncthreads();
  const int wg = wg_s;
  if (wg < 0) return;                       // extra / orphaned candidates exit
  const bool local = (loc_s >= 0);
  u64* __restrict__ mybuf = local ? (hbufL + (size_t)loc_s * 1024) : hbufG;

  const int cc   = tid >> 6;      // k-chunk 0..3
  const int lane = tid & 63;      // gate row within WG slice
  const int kb   = cc * 128;
  const int grow = (lane >> 4) * WHID + wg * 16 + (lane & 15);

  // ---- stage LDS weight half: k in [c2*128, c2*128+64), transposed ----
  for (int L = tid; L < 4096; L += 256) {
    int g = L >> 8;               // 0..15 -> k offset 4g
    int rem = L & 255;
    int c2 = rem >> 6;
    int r = rem & 63;
    int gr = (r >> 4) * WHID + wg * 16 + (r & 15);
    wlds[L] = *(const float4*)(Whh + (size_t)gr * WHID + c2 * 128 + 4 * g);
  }
  __syncthreads();
  const float* __restrict__ wsrc2 = Whh + (size_t)grow * WHID + kb + 64;

  float c_state = 0.f;            // lanes<16 of wave 0 use
  int lmode = local ? 1 : 0;      // replica lanes start optimistic-local

  for (int t = 0; t < S_LEN; ++t) {
    const int par = t & 1;
    // ---- issue loop-half weight loads + Gx BEFORE the poll: their latency
    //      hides under the poll wait (asm "memory" clobber pins them here) ----
    float4 wr_[16];
#pragma unroll
    for (int i = 0; i < 16; ++i) wr_[i] = *(const float4*)(wsrc2 + 4 * i);
    float gxv = 0.f;
    if (tid < 64)
      gxv = Gx[(size_t)t * GDIM + grow];
    // ---- poll own 2 tagged slots {lo32=value, hi32=tag} ----
    float v0 = 0.f, v1 = 0.f;
    if (t > 0) {
      const unsigned want = (unsigned)t;
      const size_t soff = (size_t)par * WHID + kb + 2 * lane;
      bool found = false;
      if (lmode) {                          // replica fast path: local L2
        const u64* pL = mybuf + soff;
        int iter = 0;
        for (;;) {
          int4 rr;
          asm volatile("global_load_dwordx4 %0, %1, off sc0\n\t"
                       "s_waitcnt vmcnt(0)"
                       : "=&v"(rr) : "v"(pL) : "memory");
          if ((unsigned)rr.y == want && (unsigned)rr.w == want) {
            v0 = __int_as_float(rr.x); v1 = __int_as_float(rr.z);
            found = true; break;
          }
          ++iter;
          if (t == 1 && iter >= 32768) { lmode = 0; break; }  // latch off
          if ((iter & 15) == 0 &&
              __hip_atomic_load(done, __ATOMIC_RELAXED,
                                __HIP_MEMORY_SCOPE_AGENT)) {
            bail_s = 1; found = true; break;   // garbage; bail after barrier
          }
        }
      }
      if (!found) {                         // backbone path / replica fallback
        const u64* pG = hbufG + soff;
        const u64* pL = mybuf + soff;
        int iter = 0;
        for (;;) {
          u64 a = __hip_atomic_load(pG + 0, __ATOMIC_RELAXED,
                                    __HIP_MEMORY_SCOPE_AGENT);
          u64 b = __hip_atomic_load(pG + 1, __ATOMIC_RELAXED,
                                    __HIP_MEMORY_SCOPE_AGENT);
          if ((unsigned)(a >> 32) == want && (unsigned)(b >> 32) == want) {
            v0 = __uint_as_float((unsigned)a);
            v1 = __uint_as_float((unsigned)b);
            break;
          }
          if (local) {                      // also try local while falling back
            int4 rr;
            asm volatile("global_load_dwordx4 %0, %1, off sc0\n\t"
                         "s_waitcnt vmcnt(0)"
                         : "=&v"(rr) : "v"(pL) : "memory");
            if ((unsigned)rr.y == want && (unsigned)rr.w == want) {
              v0 = __int_as_float(rr.x); v1 = __int_as_float(rr.z); break;
            }
            __builtin_amdgcn_s_sleep(2);    // pace: don't throttle backbone
          }
          if (((++iter) & 15) == 0 &&
              __hip_atomic_load(done, __ATOMIC_RELAXED,
                                __HIP_MEMORY_SCOPE_AGENT)) {
            bail_s = 1; break;
          }
        }
      }
    }
    // ---- stage own chunk (wave-private LDS region) ----
    *(float2*)(&h_lds[kb + 2 * lane]) = make_float2(v0, v1);
    __threadfence_block();
    // ---- matvec: LDS half then register half; h broadcast from LDS ----
    float acc = 0.f;
#pragma unroll
    for (int g = 0; g < 16; ++g) {
      const float4 wv = wlds[g * 256 + cc * 64 + lane];
      const float4 hv = *(const float4*)(&h_lds[kb + 4 * g]);
      acc = fmaf(wv.x, hv.x, acc);
      acc = fmaf(wv.y, hv.y, acc);
      acc = fmaf(wv.z, hv.z, acc);
      acc = fmaf(wv.w, hv.w, acc);
    }
#pragma unroll
    for (int i = 0; i < 16; ++i) {
      const float4 hv = *(const float4*)(&h_lds[kb + 64 + 4 * i]);
      acc = fmaf(wr_[i].x, hv.x, acc);
      acc = fmaf(wr_[i].y, hv.y, acc);
      acc = fmaf(wr_[i].z, hv.z, acc);
      acc = fmaf(wr_[i].w, hv.w, acc);
    }
    red[par][tid] = acc;
    __syncthreads();   // the ONLY barrier per step
    if (bail_s) break; // someone finished the whole problem -> exit early
    if (tid < 64) {
      const float* rp = red[par];
      float s = rp[lane] + rp[64 + lane] + rp[128 + lane] + rp[192 + lane] + gxv;
      float act = ((lane >> 4) == 2) ? tanhf_(s) : sigmoidf_(s);
      int jj = lane & 15;
      float iv = __shfl(act, jj);
      float fv = __shfl(act, 16 + jj);
      float gv = __shfl(act, 32 + jj);
      float ov = __shfl(act, 48 + jj);
      if (lane < 16) {
        c_state = fv * c_state + iv * gv;
        float hv = ov * tanhf_(c_state);
        const int hidx = wg * 16 + lane;
        const u64 pkt = ((u64)(unsigned)(t + 1) << 32) | (u64)__float_as_uint(hv);
        const size_t off = (size_t)((t + 1) & 1) * WHID + hidx;
        if (local)   // wg-scope RMW executes at this XCD's L2 (fast path)
          (void)__hip_atomic_exchange(mybuf + off, pkt, __ATOMIC_RELAXED,
                                      __HIP_MEMORY_SCOPE_WORKGROUP);
        else         // backbone: agent RMW at coherence point (mirror)
          (void)__hip_atomic_exchange(mybuf + off, pkt, __ATOMIC_RELAXED,
                                      __HIP_MEMORY_SCOPE_AGENT);
        hs[(size_t)t * WHID + hidx] = hv;  // duplicate same-value stores OK
      }
    }
  }

  // ---- completion protocol: first full group releases everyone ----
  if (tid == 0 && !bail_s) {
    const int gidx = local ? loc_s : 16;
    int r = __hip_atomic_fetch_add(&done_cnt[gidx], 1, __ATOMIC_RELAXED,
                                   __HIP_MEMORY_SCOPE_AGENT);
    if (r == NWG - 1)
      __hip_atomic_store(done, 1, __ATOMIC_RELEASE, __HIP_MEMORY_SCOPE_AGENT);
  }
}

// ---------------------------------------------------------------------------
// K4: logits + log_softmax. One 64-lane wave per row t; lane = tag.
// ---------------------------------------------------------------------------
__global__ __launch_bounds__(256)
void tag_kernel(const float* __restrict__ hs, const float* __restrict__ W,
                const float* __restrict__ b, float* __restrict__ out)
{
  const int wave = threadIdx.x >> 6;
  const int lane = threadIdx.x & 63;
  const int t = blockIdx.x * 4 + wave;
  const float* hr = hs + (size_t)t * WHID;
  const float* wr = W + (size_t)lane * WHID;
  float acc = b[lane];
  for (int k = 0; k < WHID; k += 4) {
    float4 wv = *(const float4*)(wr + k);
    float4 hv = *(const float4*)(hr + k);
    acc = fmaf(wv.x, hv.x, acc);
    acc = fmaf(wv.y, hv.y, acc);
    acc = fmaf(wv.z, hv.z, acc);
    acc = fmaf(wv.w, hv.w, acc);
  }
  float m = acc;
#pragma unroll
  for (int off = 32; off > 0; off >>= 1) m = fmaxf(m, __shfl_xor(m, off));
  float e = __expf(acc - m);
  float sum = e;
#pragma unroll
  for (int off = 32; off > 0; off >>= 1) sum += __shfl_xor(sum, off);
  out[(size_t)t * NTAG + lane] = (acc - m) - __logf(sum);
}

extern "C" void kernel_launch(void* const* d_in, const int* in_sizes, int n_in,
                              void* d_out, int out_size, void* d_ws, size_t ws_size,
                              hipStream_t stream)
{
  const int* x          = (const int*)d_in[0];
  const int* chars      = (const int*)d_in[1];
  const int* lengths    = (const int*)d_in[2];
  const float* word_emb = (const float*)d_in[3];
  const float* char_emb = (const float*)d_in[4];
  const float* c_Wih    = (const float*)d_in[5];
  const float* c_Whh    = (const float*)d_in[6];
  const float* c_bih    = (const float*)d_in[7];
  const float* c_bhh    = (const float*)d_in[8];
  const float* w_Wih    = (const float*)d_in[9];
  const float* w_Whh    = (const float*)d_in[10];
  const float* w_bih    = (const float*)d_in[11];
  const float* w_bhh    = (const float*)d_in[12];
  const float* lin_W    = (const float*)d_in[13];
  const float* lin_b    = (const float*)d_in[14];
  float* out = (float*)d_out;

  char* ws = (char*)d_ws;
  // layout: [0,64) tickets[16] | [64,132) done_cnt[17] | [132,136) done |
  //         [4096,12288) hbufG (2x512 u64) | [16384,147456) hbufL (16x1024 u64)
  //         | char_feat 4MiB | Gx 64MiB | hs 16MiB      (total ~84.2 MiB)
  int*   tickets   = (int*)ws;
  int*   done_cnt  = (int*)(ws + 64);
  int*   done      = (int*)(ws + 132);
  u64*   hbufG     = (u64*)(ws + 4096);
  u64*   hbufL     = (u64*)(ws + 16384);
  float* char_feat = (float*)(ws + 147456);
  float* Gx        = (float*)(ws + 147456 + (size_t)S_LEN * CHID * 4);
  float* hs        = (float*)(ws + 147456 + (size_t)S_LEN * CHID * 4
                                          + (size_t)S_LEN * GDIM * 4);

  // zero control block + all tagged-slot buffers every call (replay-safe)
  hipMemsetAsync(ws, 0, 147456, stream);

  char_lstm_kernel<<<S_LEN / 16, 256, 0, stream>>>(
      chars, lengths, char_emb, c_Wih, c_Whh, c_bih, c_bhh, char_feat);

  dim3 g2(GDIM / BN, S_LEN / BM);
  gx_gemm_kernel<<<g2, 256, 0, stream>>>(
      x, word_emb, char_feat, w_Wih, w_bih, w_bhh, Gx);

  word_lstm_seq<<<320, 256, 0, stream>>>(w_Whh, Gx, hs, hbufG, hbufL,
                                         tickets, done_cnt, done);

  tag_kernel<<<S_LEN / 4, 256, 0, stream>>>(hs, lin_W, lin_b, out);
}